// Round 9
// baseline (204.263 us; speedup 1.0000x reference)
//
#include <hip/hip_runtime.h>
#include <hip/hip_bf16.h>
#include <string.h>

#define NN 100000
#define NE 1600000
#define INF_ 128
#define OC 128   // NHEAD*OUT_F
#define NH 4
#define ALPHA 0.2f
#define LDA 272                      // GEMM LDS row stride in bytes

#define BSH 9
#define BINW 512                     // nodes per bin
#define NBIN ((NN + BINW - 1) / BINW)   // 196
#define EPT 16                       // edges per thread, partition kernels
#define EPB (256 * EPT)              // 4096 edges per block
#define NPB1 ((NE + EPB - 1) / EPB)  // 391 blocks
#define CAP2 12288                   // LDS staging capacity in k_part2
#define DMAX 64                      // degree buckets for node sorting

typedef __bf16 bf16x8 __attribute__((ext_vector_type(8)));
typedef float f32x4 __attribute__((ext_vector_type(4)));
typedef float f32x2 __attribute__((ext_vector_type(2)));

__device__ __forceinline__ float lrelu(float x) {
    return x > 0.0f ? x : ALPHA * x;
}
__device__ __forceinline__ unsigned short f2bf(float f) {
    __hip_bfloat16 b = __float2bfloat16(f);
    unsigned short u; memcpy(&u, &b, 2); return u;
}

// One-time: W [k][c] fp32 -> Wt [c][k] bf16 (32 KB).
__global__ __launch_bounds__(256) void k_wconv(
    const float* __restrict__ W, __hip_bfloat16* __restrict__ Wt) {
    const int i = blockIdx.x * 256 + threadIdx.x;   // < 16384
    const int co = i >> 7, ko = i & 127;
    Wt[i] = __float2bfloat16(W[ko * OC + co]);
}

// MFMA GEMM: h = x @ W (bf16 out) + fused per-(row,head) al/ar epilogue.
__global__ __launch_bounds__(256) void k_gemm(
    const float* __restrict__ x, const __hip_bfloat16* __restrict__ Wt,
    const float* __restrict__ a_l, const float* __restrict__ a_r,
    __hip_bfloat16* __restrict__ hb, float* __restrict__ al, float* __restrict__ ar) {
    __shared__ __align__(16) char sA[64 * LDA];    // x tile, bf16 [64][128]
    __shared__ __align__(16) char sB[128 * LDA];   // Wt, bf16 [col][k]
    const int tid = threadIdx.x;
    const int rowBase = blockIdx.x * 64;

    // Stage x tile (fp32 -> bf16).
    {
        union { uint2 d; unsigned short u[4]; } pk;
        for (int j = 0; j < 8; ++j) {
            const int i4 = tid + j * 256;
            const int r = i4 >> 5, c4 = i4 & 31;
            const int g = rowBase + r;
            float4 v = make_float4(0.f, 0.f, 0.f, 0.f);
            if (g < NN) v = *(const float4*)&x[(size_t)g * INF_ + c4 * 4];
            pk.u[0] = f2bf(v.x); pk.u[1] = f2bf(v.y);
            pk.u[2] = f2bf(v.z); pk.u[3] = f2bf(v.w);
            *(uint2*)(sA + r * LDA + c4 * 8) = pk.d;
        }
    }
    // Stage Wt (pure copy, coalesced).
    for (int i4 = tid; i4 < 2048; i4 += 256) {
        const int c = i4 >> 4, k4 = i4 & 15;
        *(uint4*)(sB + c * LDA + k4 * 16) =
            *(const uint4*)((const char*)Wt + (size_t)c * 256 + k4 * 16);
    }
    __syncthreads();

    const int lane = tid & 63;
    const int w = tid >> 6;
    const int arow = w * 16 + (lane & 15);
    const int koff = (lane >> 4) * 16;

    f32x4 acc[8];
#pragma unroll
    for (int n = 0; n < 8; ++n) acc[n] = (f32x4){0.f, 0.f, 0.f, 0.f};

#pragma unroll
    for (int kk = 0; kk < 4; ++kk) {
        const bf16x8 a = *(const bf16x8*)(sA + arow * LDA + kk * 64 + koff);
#pragma unroll
        for (int n = 0; n < 8; ++n) {
            const int brow = n * 16 + (lane & 15);
            const bf16x8 b = *(const bf16x8*)(sB + brow * LDA + kk * 64 + koff);
            acc[n] = __builtin_amdgcn_mfma_f32_16x16x32_bf16(a, b, acc[n], 0, 0, 0);
        }
    }

    // C store: col = n*16 + (lane&15), row = rbase + r.
    const int rbase = rowBase + w * 16 + (lane >> 4) * 4;
#pragma unroll
    for (int n = 0; n < 8; ++n) {
        const int col = n * 16 + (lane & 15);
#pragma unroll
        for (int r = 0; r < 4; ++r) {
            const int row = rbase + r;
            if (row < NN) hb[(size_t)row * OC + col] = __float2bfloat16(acc[n][r]);
        }
    }

    // Fused al/ar: head hd covers cols hd*32..hd*32+31 = fragments n=2hd,2hd+1.
    float alw[8], arw[8];
#pragma unroll
    for (int n = 0; n < 8; ++n) {
        alw[n] = a_l[n * 16 + (lane & 15)];
        arw[n] = a_r[n * 16 + (lane & 15)];
    }
#pragma unroll
    for (int r = 0; r < 4; ++r) {
        const int row = rbase + r;
#pragma unroll
        for (int hd = 0; hd < 4; ++hd) {
            float pl = acc[2 * hd][r] * alw[2 * hd] + acc[2 * hd + 1][r] * alw[2 * hd + 1];
            float pr = acc[2 * hd][r] * arw[2 * hd] + acc[2 * hd + 1][r] * arw[2 * hd + 1];
#pragma unroll
            for (int m = 1; m <= 8; m <<= 1) {
                pl += __shfl_xor(pl, m);
                pr += __shfl_xor(pr, m);
            }
            if ((lane & 15) == hd && row < NN) {
                al[row * NH + hd] = pl;
                ar[row * NH + hd] = pr;
            }
        }
    }
}

// Per-bin edge counts (LDS pre-aggregated).
__global__ __launch_bounds__(256) void k_binhist(
    const int* __restrict__ row, int* __restrict__ bincnt) {
    __shared__ int h[NBIN];
    const int t = threadIdx.x;
    for (int i = t; i < NBIN; i += 256) h[i] = 0;
    __syncthreads();
    const int base = blockIdx.x * EPB;
    for (int i = 0; i < EPT; ++i) {
        const int e = base + t + i * 256;
        if (e < NE) atomicAdd(&h[row[e] >> BSH], 1);
    }
    __syncthreads();
    for (int i = t; i < NBIN; i += 256)
        if (h[i]) atomicAdd(&bincnt[i], h[i]);
}

// Serial scan of bin counts -> binoffs, bincur; also offs[NN].
__global__ void k_binscan(const int* __restrict__ bincnt,
                          int* __restrict__ binoffs, int* __restrict__ bincur,
                          int* __restrict__ offs) {
    if (threadIdx.x == 0) {
        int acc = 0;
        for (int i = 0; i < NBIN; ++i) {
            binoffs[i] = acc; bincur[i] = acc; acc += bincnt[i];
        }
        binoffs[NBIN] = acc;   // == NE
        offs[NN] = NE;
    }
}

// Coarse partition: edges -> bin-grouped packed words ((r&511)<<17 | c).
__global__ __launch_bounds__(256) void k_part1(
    const int* __restrict__ row, const int* __restrict__ col,
    int* __restrict__ bincur, unsigned* __restrict__ tmp) {
    __shared__ int h[NBIN], gbase[NBIN], lcur[NBIN];
    const int t = threadIdx.x;
    for (int i = t; i < NBIN; i += 256) { h[i] = 0; lcur[i] = 0; }
    __syncthreads();

    const int e0 = blockIdx.x * EPB + t * EPT;
    int r[EPT], c[EPT];
    if (e0 + EPT <= NE) {
#pragma unroll
        for (int q = 0; q < EPT / 4; ++q) {
            const int4 rv = *(const int4*)&row[e0 + q * 4];
            const int4 cv = *(const int4*)&col[e0 + q * 4];
            r[q*4+0] = rv.x; r[q*4+1] = rv.y; r[q*4+2] = rv.z; r[q*4+3] = rv.w;
            c[q*4+0] = cv.x; c[q*4+1] = cv.y; c[q*4+2] = cv.z; c[q*4+3] = cv.w;
        }
    } else {
#pragma unroll
        for (int i = 0; i < EPT; ++i) {
            const int e = e0 + i;
            r[i] = (e < NE) ? row[e] : -1;
            c[i] = (e < NE) ? col[e] : 0;
        }
    }
#pragma unroll
    for (int i = 0; i < EPT; ++i)
        if (r[i] >= 0) atomicAdd(&h[r[i] >> BSH], 1);
    __syncthreads();
    for (int i = t; i < NBIN; i += 256)
        if (h[i]) gbase[i] = atomicAdd(&bincur[i], h[i]);
    __syncthreads();
#pragma unroll
    for (int i = 0; i < EPT; ++i) {
        if (r[i] < 0) continue;
        const int b = r[i] >> BSH;
        const int pos = atomicAdd(&lcur[b], 1);
        tmp[gbase[b] + pos] =
            ((unsigned)(r[i] & (BINW - 1)) << 17) | (unsigned)c[i];
    }
}

// Fine partition: one block per bin; emits node-sorted cols_s + per-node offs
// + degree-bucket histogram (for the node permutation).
__global__ __launch_bounds__(256) void k_part2(
    const unsigned* __restrict__ tmp, const int* __restrict__ binoffs,
    int* __restrict__ offs, int* __restrict__ cols_s, int* __restrict__ dcnt) {
    __shared__ unsigned stage[CAP2];          // 48 KB
    __shared__ int h[BINW], ps[256], cur[BINW], dh[DMAX];
    const int b = blockIdx.x, t = threadIdx.x;
    const int node0 = b * BINW;
    const int gs = binoffs[b], ge = binoffs[b + 1];
    const int cnt = ge - gs;
    for (int i = t; i < BINW; i += 256) h[i] = 0;
    if (t < DMAX) dh[t] = 0;
    __syncthreads();
    for (int j = t; j < cnt; j += 256) {
        const unsigned p = tmp[gs + j];
        if (j < CAP2) stage[j] = p;
        atomicAdd(&h[p >> 17], 1);
    }
    __syncthreads();
    // degree histogram (real nodes only)
    for (int i = t; i < BINW; i += 256)
        if (node0 + i < NN) atomicAdd(&dh[min(h[i], DMAX - 1)], 1);
    // exclusive scan over 512 via 256 pair-sums
    const int a0 = h[2 * t], a1 = h[2 * t + 1];
    ps[t] = a0 + a1;
    __syncthreads();
    for (int o = 1; o < 256; o <<= 1) {
        const int add = (t >= o) ? ps[t - o] : 0;
        __syncthreads();
        ps[t] += add;
        __syncthreads();
    }
    const int ex = ps[t] - a0 - a1 + gs;
    cur[2 * t] = ex;
    cur[2 * t + 1] = ex + a0;
    if (node0 + 2 * t < NN)     offs[node0 + 2 * t]     = ex;
    if (node0 + 2 * t + 1 < NN) offs[node0 + 2 * t + 1] = ex + a0;
    __syncthreads();
    for (int j = t; j < cnt; j += 256) {
        const unsigned p = (j < CAP2) ? stage[j] : tmp[gs + j];
        const int pos = atomicAdd(&cur[p >> 17], 1);
        cols_s[pos] = (int)(p & 0x1FFFFu);
    }
    if (t < DMAX && dh[t]) atomicAdd(&dcnt[t], dh[t]);
}

// Serial scan of degree buckets.
__global__ void k_degscan(const int* __restrict__ dcnt, int* __restrict__ dcur) {
    if (threadIdx.x == 0) {
        int acc = 0;
        for (int i = 0; i < DMAX; ++i) { dcur[i] = acc; acc += dcnt[i]; }
    }
}

// Scatter nodes into degree-sorted permutation.
__global__ __launch_bounds__(256) void k_degscatter(
    const int* __restrict__ offs, int* __restrict__ dcur, int* __restrict__ perm) {
    __shared__ int h[DMAX], gbase[DMAX], lcur[DMAX];
    const int t = threadIdx.x;
    if (t < DMAX) { h[t] = 0; lcur[t] = 0; }
    __syncthreads();
    const int n = blockIdx.x * 256 + t;
    int d = -1;
    if (n < NN) {
        d = min(offs[n + 1] - offs[n], DMAX - 1);
        atomicAdd(&h[d], 1);
    }
    __syncthreads();
    if (t < DMAX && h[t]) gbase[t] = atomicAdd(&dcur[t], h[t]);
    __syncthreads();
    if (n >= 0 && n < NN) {
        const int pos = gbase[d] + atomicAdd(&lcur[d], 1);
        perm[pos] = n;
    }
}

// Fused score + softmax + aggregation: 16-lane group per node (degree-sorted),
// 2-deep software pipeline on the cols->ar->exp chain.
__global__ __launch_bounds__(256) void k_agg(
    const int* __restrict__ perm, const int* __restrict__ offs,
    const int* __restrict__ cols_s,
    const float* __restrict__ al, const float* __restrict__ ar,
    const __hip_bfloat16* __restrict__ hb, float* __restrict__ out) {
    const int w = threadIdx.x >> 6;
    const int lane = threadIdx.x & 63;
    const int g = lane >> 4;            // node slot within wave
    const int sl = lane & 15;           // sublane within group
    const int gi = blockIdx.x * 16 + w * 4 + g;
    const bool valid = gi < NN;
    const int node = valid ? perm[gi] : 0;

    int start = 0, deg = 0;
    if (valid) {
        start = offs[node];
        deg = offs[node + 1] - start;
    }
    const int je = sl >> 2;             // edge slot this lane scores
    const int sh = sl & 3;              // head this lane scores
    const int hsel = je;                // head this lane accumulates
    const int sbase = lane & 48;        // group base lane
    const float al_sh = valid ? al[node * NH + sh] : 0.f;
    const char* hrow = (const char*)hb + sl * 16;   // lane's 16B slice

    f32x2 a0 = {0.f, 0.f}, a1 = {0.f, 0.f}, a2 = {0.f, 0.f}, a3 = {0.f, 0.f};
    float ssum = 0.f;

    // pipeline prologue: chunks 0 and 4
    int c0 = 0, c1 = 0;
    float q0 = 0.f, q1 = 0.f;
    if (je < deg)     c0 = cols_s[start + je];
    if (4 + je < deg) c1 = cols_s[start + 4 + je];
    if (je < deg)     q0 = ar[c0 * NH + sh];
    if (4 + je < deg) q1 = ar[c1 * NH + sh];

    for (int kk = 0; __any(kk < deg); kk += 8) {
        const int k2 = kk + 8 + je, k3 = kk + 12 + je;
        int c2 = 0, c3 = 0;
        if (k2 < deg) c2 = cols_s[start + k2];
        if (k3 < deg) c3 = cols_s[start + k3];
        // chunk A (edges kk..kk+3)
        {
            const float wv = (kk + je < deg) ? __expf(lrelu(al_sh + q0)) : 0.f;
#pragma unroll
            for (int j = 0; j < 4; ++j) {
                const float wj = __shfl(wv, sbase + j * 4 + hsel);
                const int   cj = __shfl(c0, sbase + j * 4);
                const uint4 v = *(const uint4*)(hrow + (size_t)cj * 256);
                a0 += wj * (f32x2){__uint_as_float(v.x << 16), __uint_as_float(v.x & 0xffff0000u)};
                a1 += wj * (f32x2){__uint_as_float(v.y << 16), __uint_as_float(v.y & 0xffff0000u)};
                a2 += wj * (f32x2){__uint_as_float(v.z << 16), __uint_as_float(v.z & 0xffff0000u)};
                a3 += wj * (f32x2){__uint_as_float(v.w << 16), __uint_as_float(v.w & 0xffff0000u)};
                ssum += wj;
            }
        }
        float q2 = 0.f;
        if (k2 < deg) q2 = ar[c2 * NH + sh];
        // chunk B (edges kk+4..kk+7)
        if (__any(kk + 4 < deg)) {
            const float wv = (kk + 4 + je < deg) ? __expf(lrelu(al_sh + q1)) : 0.f;
#pragma unroll
            for (int j = 0; j < 4; ++j) {
                const float wj = __shfl(wv, sbase + j * 4 + hsel);
                const int   cj = __shfl(c1, sbase + j * 4);
                const uint4 v = *(const uint4*)(hrow + (size_t)cj * 256);
                a0 += wj * (f32x2){__uint_as_float(v.x << 16), __uint_as_float(v.x & 0xffff0000u)};
                a1 += wj * (f32x2){__uint_as_float(v.y << 16), __uint_as_float(v.y & 0xffff0000u)};
                a2 += wj * (f32x2){__uint_as_float(v.z << 16), __uint_as_float(v.z & 0xffff0000u)};
                a3 += wj * (f32x2){__uint_as_float(v.w << 16), __uint_as_float(v.w & 0xffff0000u)};
                ssum += wj;
            }
        }
        float q3 = 0.f;
        if (k3 < deg) q3 = ar[c3 * NH + sh];
        c0 = c2; q0 = q2; c1 = c3; q1 = q3;
    }

    if (valid) {
        const float inv = (ssum > 0.f) ? 1.0f / ssum : 0.f;
        float4 o0, o1;
        o0.x = a0.x * inv; o0.y = a0.y * inv; o0.z = a1.x * inv; o0.w = a1.y * inv;
        o1.x = a2.x * inv; o1.y = a2.y * inv; o1.z = a3.x * inv; o1.w = a3.y * inv;
        float* dst = out + (size_t)node * OC + sl * 8;
        *(float4*)dst = o0;
        *(float4*)(dst + 4) = o1;
    }
}

extern "C" void kernel_launch(void* const* d_in, const int* in_sizes, int n_in,
                              void* d_out, int out_size, void* d_ws, size_t ws_size,
                              hipStream_t stream) {
    const float* x    = (const float*)d_in[0];
    const int*   ei   = (const int*)d_in[1];    // [2, NE]
    const float* W    = (const float*)d_in[2];
    const float* a_l  = (const float*)d_in[3];
    const float* a_r  = (const float*)d_in[4];
    float* out = (float*)d_out;

    const int* row = ei;         // destination
    const int* col = ei + NE;    // source

    char* ws = (char*)d_ws;
    __hip_bfloat16* hb = (__hip_bfloat16*)ws;   ws += (size_t)NN * OC * 2;   // 25.6 MB
    __hip_bfloat16* Wt = (__hip_bfloat16*)ws;   ws += (size_t)INF_ * OC * 2; // 32 KB
    float*    al      = (float*)ws;             ws += (size_t)NN * NH * 4;
    float*    ar      = (float*)ws;             ws += (size_t)NN * NH * 4;
    int*      cols_s  = (int*)ws;               ws += (size_t)NE * 4;        // 6.4 MB
    unsigned* tmp     = (unsigned*)ws;          ws += (size_t)NE * 4;        // 6.4 MB
    int*      offs    = (int*)ws;               ws += (size_t)(NN + 1) * 4;
    int*      perm    = (int*)ws;               ws += (size_t)NN * 4;
    int*      bincnt  = (int*)ws;               ws += (size_t)(NBIN + 1) * 4;
    int*      binoffs = (int*)ws;               ws += (size_t)(NBIN + 1) * 4;
    int*      bincur  = (int*)ws;               ws += (size_t)NBIN * 4;
    int*      dcnt    = (int*)ws;               ws += (size_t)DMAX * 4;
    int*      dcur    = (int*)ws;               ws += (size_t)DMAX * 4;

    hipMemsetAsync(bincnt, 0, (size_t)NBIN * 4, stream);
    hipMemsetAsync(dcnt, 0, (size_t)DMAX * 4, stream);

    k_wconv<<<64, 256, 0, stream>>>(W, Wt);
    k_gemm<<<(NN + 63) / 64, 256, 0, stream>>>(x, Wt, a_l, a_r, hb, al, ar);
    k_binhist<<<NPB1, 256, 0, stream>>>(row, bincnt);
    k_binscan<<<1, 64, 0, stream>>>(bincnt, binoffs, bincur, offs);
    k_part1<<<NPB1, 256, 0, stream>>>(row, col, bincur, tmp);
    k_part2<<<NBIN, 256, 0, stream>>>(tmp, binoffs, offs, cols_s, dcnt);
    k_degscan<<<1, 64, 0, stream>>>(dcnt, dcur);
    k_degscatter<<<(NN + 255) / 256, 256, 0, stream>>>(offs, dcur, perm);
    k_agg<<<(NN + 15) / 16, 256, 0, stream>>>(perm, offs, cols_s, al, ar, hb, out);
}

// Round 10
// 180.253 us; speedup vs baseline: 1.1332x; 1.1332x over previous
//
#include <hip/hip_runtime.h>
#include <hip/hip_bf16.h>
#include <string.h>

#define NN 100000
#define NE 1600000
#define INF_ 128
#define OC 128   // NHEAD*OUT_F
#define NH 4
#define ALPHA 0.2f
#define LDA 272                      // GEMM LDS row stride in bytes

#define BSH 9
#define BINW 512                     // nodes per bin
#define NBIN ((NN + BINW - 1) / BINW)   // 196
#define EPT 16                       // edges per thread, partition kernels
#define EPB (256 * EPT)              // 4096 edges per block
#define NPB1 ((NE + EPB - 1) / EPB)  // 391 blocks
#define CAP2 12288                   // LDS staging capacity in k_part2

typedef __bf16 bf16x8 __attribute__((ext_vector_type(8)));
typedef float f32x4 __attribute__((ext_vector_type(4)));
typedef float f32x2 __attribute__((ext_vector_type(2)));

__device__ __forceinline__ float lrelu(float x) {
    return x > 0.0f ? x : ALPHA * x;
}
__device__ __forceinline__ unsigned short f2bf(float f) {
    __hip_bfloat16 b = __float2bfloat16(f);
    unsigned short u; memcpy(&u, &b, 2); return u;
}

// One-time: W [k][c] fp32 -> Wt [c][k] bf16 (32 KB).
__global__ __launch_bounds__(256) void k_wconv(
    const float* __restrict__ W, __hip_bfloat16* __restrict__ Wt) {
    const int i = blockIdx.x * 256 + threadIdx.x;   // < 16384
    const int co = i >> 7, ko = i & 127;
    Wt[i] = __float2bfloat16(W[ko * OC + co]);
}

// MFMA GEMM: h = x @ W (bf16 out) + fused per-(row,head) al/ar epilogue.
__global__ __launch_bounds__(256) void k_gemm(
    const float* __restrict__ x, const __hip_bfloat16* __restrict__ Wt,
    const float* __restrict__ a_l, const float* __restrict__ a_r,
    __hip_bfloat16* __restrict__ hb, float* __restrict__ al, float* __restrict__ ar) {
    __shared__ __align__(16) char sA[64 * LDA];    // x tile, bf16 [64][128]
    __shared__ __align__(16) char sB[128 * LDA];   // Wt, bf16 [col][k]
    const int tid = threadIdx.x;
    const int rowBase = blockIdx.x * 64;

    // Stage x tile (fp32 -> bf16).
    {
        union { uint2 d; unsigned short u[4]; } pk;
        for (int j = 0; j < 8; ++j) {
            const int i4 = tid + j * 256;
            const int r = i4 >> 5, c4 = i4 & 31;
            const int g = rowBase + r;
            float4 v = make_float4(0.f, 0.f, 0.f, 0.f);
            if (g < NN) v = *(const float4*)&x[(size_t)g * INF_ + c4 * 4];
            pk.u[0] = f2bf(v.x); pk.u[1] = f2bf(v.y);
            pk.u[2] = f2bf(v.z); pk.u[3] = f2bf(v.w);
            *(uint2*)(sA + r * LDA + c4 * 8) = pk.d;
        }
    }
    // Stage Wt (pure copy, coalesced).
    for (int i4 = tid; i4 < 2048; i4 += 256) {
        const int c = i4 >> 4, k4 = i4 & 15;
        *(uint4*)(sB + c * LDA + k4 * 16) =
            *(const uint4*)((const char*)Wt + (size_t)c * 256 + k4 * 16);
    }
    __syncthreads();

    const int lane = tid & 63;
    const int w = tid >> 6;
    const int arow = w * 16 + (lane & 15);
    const int koff = (lane >> 4) * 16;

    f32x4 acc[8];
#pragma unroll
    for (int n = 0; n < 8; ++n) acc[n] = (f32x4){0.f, 0.f, 0.f, 0.f};

#pragma unroll
    for (int kk = 0; kk < 4; ++kk) {
        const bf16x8 a = *(const bf16x8*)(sA + arow * LDA + kk * 64 + koff);
#pragma unroll
        for (int n = 0; n < 8; ++n) {
            const int brow = n * 16 + (lane & 15);
            const bf16x8 b = *(const bf16x8*)(sB + brow * LDA + kk * 64 + koff);
            acc[n] = __builtin_amdgcn_mfma_f32_16x16x32_bf16(a, b, acc[n], 0, 0, 0);
        }
    }

    // C store: col = n*16 + (lane&15), row = rbase + r.
    const int rbase = rowBase + w * 16 + (lane >> 4) * 4;
#pragma unroll
    for (int n = 0; n < 8; ++n) {
        const int col = n * 16 + (lane & 15);
#pragma unroll
        for (int r = 0; r < 4; ++r) {
            const int row = rbase + r;
            if (row < NN) hb[(size_t)row * OC + col] = __float2bfloat16(acc[n][r]);
        }
    }

    // Fused al/ar: head hd covers cols hd*32..hd*32+31 = fragments n=2hd,2hd+1.
    float alw[8], arw[8];
#pragma unroll
    for (int n = 0; n < 8; ++n) {
        alw[n] = a_l[n * 16 + (lane & 15)];
        arw[n] = a_r[n * 16 + (lane & 15)];
    }
#pragma unroll
    for (int r = 0; r < 4; ++r) {
        const int row = rbase + r;
#pragma unroll
        for (int hd = 0; hd < 4; ++hd) {
            float pl = acc[2 * hd][r] * alw[2 * hd] + acc[2 * hd + 1][r] * alw[2 * hd + 1];
            float pr = acc[2 * hd][r] * arw[2 * hd] + acc[2 * hd + 1][r] * arw[2 * hd + 1];
#pragma unroll
            for (int m = 1; m <= 8; m <<= 1) {
                pl += __shfl_xor(pl, m);
                pr += __shfl_xor(pr, m);
            }
            if ((lane & 15) == hd && row < NN) {
                al[row * NH + hd] = pl;
                ar[row * NH + hd] = pr;
            }
        }
    }
}

// Per-bin edge counts (LDS pre-aggregated).
__global__ __launch_bounds__(256) void k_binhist(
    const int* __restrict__ row, int* __restrict__ bincnt) {
    __shared__ int h[NBIN];
    const int t = threadIdx.x;
    for (int i = t; i < NBIN; i += 256) h[i] = 0;
    __syncthreads();
    const int base = blockIdx.x * EPB;
    for (int i = 0; i < EPT; ++i) {
        const int e = base + t + i * 256;
        if (e < NE) atomicAdd(&h[row[e] >> BSH], 1);
    }
    __syncthreads();
    for (int i = t; i < NBIN; i += 256)
        if (h[i]) atomicAdd(&bincnt[i], h[i]);
}

// Parallel scan of bin counts -> binoffs, bincur; also offs[NN].
__global__ __launch_bounds__(256) void k_binscan(
    const int* __restrict__ bincnt, int* __restrict__ binoffs,
    int* __restrict__ bincur, int* __restrict__ offs) {
    __shared__ int ts[256];
    const int t = threadIdx.x;
    const int v = (t < NBIN) ? bincnt[t] : 0;
    ts[t] = v;
    __syncthreads();
    for (int o = 1; o < 256; o <<= 1) {
        const int add = (t >= o) ? ts[t - o] : 0;
        __syncthreads();
        ts[t] += add;
        __syncthreads();
    }
    const int ex = ts[t] - v;
    if (t < NBIN) { binoffs[t] = ex; bincur[t] = ex; }
    if (t == 255) {
        binoffs[NBIN] = ts[255];   // == NE
        offs[NN] = NE;
    }
}

// Coarse partition: edges -> bin-grouped packed words ((r&511)<<17 | c).
__global__ __launch_bounds__(256) void k_part1(
    const int* __restrict__ row, const int* __restrict__ col,
    int* __restrict__ bincur, unsigned* __restrict__ tmp) {
    __shared__ int h[NBIN], gbase[NBIN], lcur[NBIN];
    const int t = threadIdx.x;
    for (int i = t; i < NBIN; i += 256) { h[i] = 0; lcur[i] = 0; }
    __syncthreads();

    const int e0 = blockIdx.x * EPB + t * EPT;
    int r[EPT], c[EPT];
    if (e0 + EPT <= NE) {
#pragma unroll
        for (int q = 0; q < EPT / 4; ++q) {
            const int4 rv = *(const int4*)&row[e0 + q * 4];
            const int4 cv = *(const int4*)&col[e0 + q * 4];
            r[q*4+0] = rv.x; r[q*4+1] = rv.y; r[q*4+2] = rv.z; r[q*4+3] = rv.w;
            c[q*4+0] = cv.x; c[q*4+1] = cv.y; c[q*4+2] = cv.z; c[q*4+3] = cv.w;
        }
    } else {
#pragma unroll
        for (int i = 0; i < EPT; ++i) {
            const int e = e0 + i;
            r[i] = (e < NE) ? row[e] : -1;
            c[i] = (e < NE) ? col[e] : 0;
        }
    }
#pragma unroll
    for (int i = 0; i < EPT; ++i)
        if (r[i] >= 0) atomicAdd(&h[r[i] >> BSH], 1);
    __syncthreads();
    for (int i = t; i < NBIN; i += 256)
        if (h[i]) gbase[i] = atomicAdd(&bincur[i], h[i]);
    __syncthreads();
#pragma unroll
    for (int i = 0; i < EPT; ++i) {
        if (r[i] < 0) continue;
        const int b = r[i] >> BSH;
        const int pos = atomicAdd(&lcur[b], 1);
        tmp[gbase[b] + pos] =
            ((unsigned)(r[i] & (BINW - 1)) << 17) | (unsigned)c[i];
    }
}

// Fine partition: one block per bin; emits node-sorted cols_s + per-node offs.
__global__ __launch_bounds__(256) void k_part2(
    const unsigned* __restrict__ tmp, const int* __restrict__ binoffs,
    int* __restrict__ offs, int* __restrict__ cols_s) {
    __shared__ unsigned stage[CAP2];          // 48 KB
    __shared__ int h[BINW], ps[256], cur[BINW];
    const int b = blockIdx.x, t = threadIdx.x;
    const int node0 = b * BINW;
    const int gs = binoffs[b], ge = binoffs[b + 1];
    const int cnt = ge - gs;
    for (int i = t; i < BINW; i += 256) h[i] = 0;
    __syncthreads();
    for (int j = t; j < cnt; j += 256) {
        const unsigned p = tmp[gs + j];
        if (j < CAP2) stage[j] = p;
        atomicAdd(&h[p >> 17], 1);
    }
    __syncthreads();
    const int a0 = h[2 * t], a1 = h[2 * t + 1];
    ps[t] = a0 + a1;
    __syncthreads();
    for (int o = 1; o < 256; o <<= 1) {
        const int add = (t >= o) ? ps[t - o] : 0;
        __syncthreads();
        ps[t] += add;
        __syncthreads();
    }
    const int ex = ps[t] - a0 - a1 + gs;
    cur[2 * t] = ex;
    cur[2 * t + 1] = ex + a0;
    if (node0 + 2 * t < NN)     offs[node0 + 2 * t]     = ex;
    if (node0 + 2 * t + 1 < NN) offs[node0 + 2 * t + 1] = ex + a0;
    __syncthreads();
    for (int j = t; j < cnt; j += 256) {
        const unsigned p = (j < CAP2) ? stage[j] : tmp[gs + j];
        const int pos = atomicAdd(&cur[p >> 17], 1);
        cols_s[pos] = (int)(p & 0x1FFFFu);
    }
}

// Fused score + softmax + aggregation: 16-lane group per node, natural order,
// 2-deep software pipeline on the cols->ar->exp chain.
__global__ __launch_bounds__(256) void k_agg(
    const int* __restrict__ offs, const int* __restrict__ cols_s,
    const float* __restrict__ al, const float* __restrict__ ar,
    const __hip_bfloat16* __restrict__ hb, float* __restrict__ out) {
    const int w = threadIdx.x >> 6;
    const int lane = threadIdx.x & 63;
    const int g = lane >> 4;            // node slot within wave
    const int sl = lane & 15;           // sublane within group
    const int node = blockIdx.x * 16 + w * 4 + g;
    const bool valid = node < NN;

    int start = 0, deg = 0;
    if (valid) {
        start = offs[node];
        deg = offs[node + 1] - start;
    }
    const int je = sl >> 2;             // edge slot this lane scores
    const int sh = sl & 3;              // head this lane scores
    const int hsel = je;                // head this lane accumulates
    const int sbase = lane & 48;        // group base lane
    const float al_sh = valid ? al[node * NH + sh] : 0.f;
    const char* hrow = (const char*)hb + sl * 16;   // lane's 16B slice

    f32x2 a0 = {0.f, 0.f}, a1 = {0.f, 0.f}, a2 = {0.f, 0.f}, a3 = {0.f, 0.f};
    float ssum = 0.f;

    // pipeline prologue: chunks 0 and 4
    int c0 = 0, c1 = 0;
    float q0 = 0.f, q1 = 0.f;
    if (je < deg)     c0 = cols_s[start + je];
    if (4 + je < deg) c1 = cols_s[start + 4 + je];
    if (je < deg)     q0 = ar[c0 * NH + sh];
    if (4 + je < deg) q1 = ar[c1 * NH + sh];

    for (int kk = 0; __any(kk < deg); kk += 8) {
        const int k2 = kk + 8 + je, k3 = kk + 12 + je;
        int c2 = 0, c3 = 0;
        if (k2 < deg) c2 = cols_s[start + k2];
        if (k3 < deg) c3 = cols_s[start + k3];
        // chunk A (edges kk..kk+3)
        {
            const float wv = (kk + je < deg) ? __expf(lrelu(al_sh + q0)) : 0.f;
#pragma unroll
            for (int j = 0; j < 4; ++j) {
                const float wj = __shfl(wv, sbase + j * 4 + hsel);
                const int   cj = __shfl(c0, sbase + j * 4);
                const uint4 v = *(const uint4*)(hrow + (size_t)cj * 256);
                a0 += wj * (f32x2){__uint_as_float(v.x << 16), __uint_as_float(v.x & 0xffff0000u)};
                a1 += wj * (f32x2){__uint_as_float(v.y << 16), __uint_as_float(v.y & 0xffff0000u)};
                a2 += wj * (f32x2){__uint_as_float(v.z << 16), __uint_as_float(v.z & 0xffff0000u)};
                a3 += wj * (f32x2){__uint_as_float(v.w << 16), __uint_as_float(v.w & 0xffff0000u)};
                ssum += wj;
            }
        }
        float q2 = 0.f;
        if (k2 < deg) q2 = ar[c2 * NH + sh];
        // chunk B (edges kk+4..kk+7)
        if (__any(kk + 4 < deg)) {
            const float wv = (kk + 4 + je < deg) ? __expf(lrelu(al_sh + q1)) : 0.f;
#pragma unroll
            for (int j = 0; j < 4; ++j) {
                const float wj = __shfl(wv, sbase + j * 4 + hsel);
                const int   cj = __shfl(c1, sbase + j * 4);
                const uint4 v = *(const uint4*)(hrow + (size_t)cj * 256);
                a0 += wj * (f32x2){__uint_as_float(v.x << 16), __uint_as_float(v.x & 0xffff0000u)};
                a1 += wj * (f32x2){__uint_as_float(v.y << 16), __uint_as_float(v.y & 0xffff0000u)};
                a2 += wj * (f32x2){__uint_as_float(v.z << 16), __uint_as_float(v.z & 0xffff0000u)};
                a3 += wj * (f32x2){__uint_as_float(v.w << 16), __uint_as_float(v.w & 0xffff0000u)};
                ssum += wj;
            }
        }
        float q3 = 0.f;
        if (k3 < deg) q3 = ar[c3 * NH + sh];
        c0 = c2; q0 = q2; c1 = c3; q1 = q3;
    }

    if (valid) {
        const float inv = (ssum > 0.f) ? 1.0f / ssum : 0.f;
        float4 o0, o1;
        o0.x = a0.x * inv; o0.y = a0.y * inv; o0.z = a1.x * inv; o0.w = a1.y * inv;
        o1.x = a2.x * inv; o1.y = a2.y * inv; o1.z = a3.x * inv; o1.w = a3.y * inv;
        float* dst = out + (size_t)node * OC + sl * 8;
        *(float4*)dst = o0;
        *(float4*)(dst + 4) = o1;
    }
}

extern "C" void kernel_launch(void* const* d_in, const int* in_sizes, int n_in,
                              void* d_out, int out_size, void* d_ws, size_t ws_size,
                              hipStream_t stream) {
    const float* x    = (const float*)d_in[0];
    const int*   ei   = (const int*)d_in[1];    // [2, NE]
    const float* W    = (const float*)d_in[2];
    const float* a_l  = (const float*)d_in[3];
    const float* a_r  = (const float*)d_in[4];
    float* out = (float*)d_out;

    const int* row = ei;         // destination
    const int* col = ei + NE;    // source

    char* ws = (char*)d_ws;
    __hip_bfloat16* hb = (__hip_bfloat16*)ws;   ws += (size_t)NN * OC * 2;   // 25.6 MB
    __hip_bfloat16* Wt = (__hip_bfloat16*)ws;   ws += (size_t)INF_ * OC * 2; // 32 KB
    float*    al      = (float*)ws;             ws += (size_t)NN * NH * 4;
    float*    ar      = (float*)ws;             ws += (size_t)NN * NH * 4;
    int*      cols_s  = (int*)ws;               ws += (size_t)NE * 4;        // 6.4 MB
    unsigned* tmp     = (unsigned*)ws;          ws += (size_t)NE * 4;        // 6.4 MB
    int*      offs    = (int*)ws;               ws += (size_t)(NN + 1) * 4;
    int*      bincnt  = (int*)ws;               ws += (size_t)(NBIN + 1) * 4;
    int*      binoffs = (int*)ws;               ws += (size_t)(NBIN + 1) * 4;
    int*      bincur  = (int*)ws;               ws += (size_t)NBIN * 4;

    hipMemsetAsync(bincnt, 0, (size_t)NBIN * 4, stream);

    k_wconv<<<64, 256, 0, stream>>>(W, Wt);
    k_gemm<<<(NN + 63) / 64, 256, 0, stream>>>(x, Wt, a_l, a_r, hb, al, ar);
    k_binhist<<<NPB1, 256, 0, stream>>>(row, bincnt);
    k_binscan<<<1, 256, 0, stream>>>(bincnt, binoffs, bincur, offs);
    k_part1<<<NPB1, 256, 0, stream>>>(row, col, bincur, tmp);
    k_part2<<<NBIN, 256, 0, stream>>>(tmp, binoffs, offs, cols_s);
    k_agg<<<(NN + 15) / 16, 256, 0, stream>>>(offs, cols_s, al, ar, hb, out);
}